// Round 16
// baseline (209.688 us; speedup 1.0000x reference)
//
#include <hip/hip_runtime.h>
#include <hip/hip_bf16.h>

typedef __bf16 bf16;
typedef __bf16 bf16x8 __attribute__((ext_vector_type(8)));
typedef float  f32x4  __attribute__((ext_vector_type(4)));
typedef float  f32x2  __attribute__((ext_vector_type(2)));

#define LOG2E        1.4426950408889634f
#define QSCALE_LOG2E 0.18033688011112043f   /* log2(e)/8 */
#define DEFER_THR    20.0f                  /* rescale only if logit2 > m+20 */

// async global->LDS, 16B per lane; LDS dest = uniform base + lane*16
#define GLDS(g, l)                                                        \
  __builtin_amdgcn_global_load_lds(                                       \
      (const __attribute__((address_space(1))) void*)(g),                 \
      (__attribute__((address_space(3))) void*)(l), 16, 0, 0)

#define WAITV(n) asm volatile("s_waitcnt vmcnt(" #n ")" ::: "memory")
#define BARRIER() do {                                                    \
  __builtin_amdgcn_s_barrier();                                           \
  __builtin_amdgcn_sched_barrier(0);                                      \
} while (0)

// ---------------------------------------------------------------------------
// LDS staging helpers (XOR-swizzled bf16 tiles; known good)
// ---------------------------------------------------------------------------
__device__ __forceinline__ void stage_f32_tile(const float* __restrict__ src, int ld,
                                               char* dst, int tid) {
  #pragma unroll
  for (int t = 0; t < 8; ++t) {
    int c8  = tid + t * 256;
    int row = c8 >> 4;
    int h8  = c8 & 15;
    const f32x4 v = *reinterpret_cast<const f32x4*>(src + row * ld + h8 * 4);
    union { bf16 h[4]; unsigned long long u; } pk;
    pk.h[0] = (bf16)v[0]; pk.h[1] = (bf16)v[1];
    pk.h[2] = (bf16)v[2]; pk.h[3] = (bf16)v[3];
    int byte = (row << 7) + ((((h8 >> 1) ^ (row & 7)) << 4) | ((h8 & 1) << 3));
    *reinterpret_cast<unsigned long long*>(dst + byte) = pk.u;
  }
}

// 256-row variant (proj v3 A-tile)
__device__ __forceinline__ void stage_f32_tile256(const float* __restrict__ src, int ld,
                                                  char* dst, int tid) {
  #pragma unroll
  for (int t = 0; t < 16; ++t) {
    int c8  = tid + t * 256;
    int row = c8 >> 4;
    int h8  = c8 & 15;
    const f32x4 v = *reinterpret_cast<const f32x4*>(src + row * ld + h8 * 4);
    union { bf16 h[4]; unsigned long long u; } pk;
    pk.h[0] = (bf16)v[0]; pk.h[1] = (bf16)v[1];
    pk.h[2] = (bf16)v[2]; pk.h[3] = (bf16)v[3];
    int byte = (row << 7) + ((((h8 >> 1) ^ (row & 7)) << 4) | ((h8 & 1) << 3));
    *reinterpret_cast<unsigned long long*>(dst + byte) = pk.u;
  }
}

__device__ __forceinline__ void stage_bf16_tile(const bf16* __restrict__ src, int ld,
                                                char* dst, int tid) {
  #pragma unroll
  for (int t = 0; t < 4; ++t) {
    int c   = tid + t * 256;
    int row = c >> 3;
    int ck  = c & 7;
    const bf16x8 v = *reinterpret_cast<const bf16x8*>(src + row * ld + ck * 8);
    int byte = (row << 7) + (((ck ^ (row & 7)) << 4));
    *reinterpret_cast<bf16x8*>(dst + byte) = v;
  }
}

// ---------------------------------------------------------------------------
// Kernel 1 (v3): 5 projection GEMMs, 256-row x 128-col blocks.
// W panel re-reads halve twice vs r9 (64 -> 16 readers per slab):
// W VMEM traffic 320 -> 160 MB against the per-CU TA ingest path.
// grid = 5 * 32 * 4 = 640 blocks, 4 waves; per wave acc[8][4].
// LDS = 32KB A + 16KB W = 48KB. Epilogue scatter unchanged (pre-swizzled ws).
// ---------------------------------------------------------------------------
__global__ __launch_bounds__(256) void proj_gemm(
    const float* __restrict__ qc, const float* __restrict__ qp,
    const float* __restrict__ kc, const float* __restrict__ kp,
    const float* __restrict__ vin,
    const float* __restrict__ Wqc, const float* __restrict__ bqc,
    const float* __restrict__ Wqp, const float* __restrict__ bqp,
    const float* __restrict__ Wkc, const float* __restrict__ bkc,
    const float* __restrict__ Wkp, const float* __restrict__ bkp,
    const float* __restrict__ Wv,  const float* __restrict__ bv,
    bf16* __restrict__ Qws, bf16* __restrict__ Kws, bf16* __restrict__ Vtws) {
  __shared__ __align__(16) bf16 lA[256 * 64];   // 32 KB
  __shared__ __align__(16) bf16 lB[128 * 64];   // 16 KB
  char* lAb = (char*)lA;
  char* lBb = (char*)lB;

  const int bxr = blockIdx.x;                   // XCD = bxr % 8
  const int bx  = (bxr & 7) * 80 + (bxr >> 3);  // bijective chunked swizzle
  const int g  = bx >> 7;                       // 128 blocks per gemm
  const int mt = (bx & 127) >> 2;               // 32 M-tiles of 256 rows
  const int nt = bx & 3;                        // 4 N-tiles of 128 cols

  const float *A, *W, *bias;
  if      (g == 0) { A = qc;  W = Wqc; bias = bqc; }
  else if (g == 1) { A = qp;  W = Wqp; bias = bqp; }
  else if (g == 2) { A = kc;  W = Wkc; bias = bkc; }
  else if (g == 3) { A = kp;  W = Wkp; bias = bkp; }
  else             { A = vin; W = Wv;  bias = bv;  }

  const int tid  = threadIdx.x;
  const int lane = tid & 63, wid = tid >> 6;
  const int wr = wid >> 1, wc = wid & 1;        // wr: 128-row half, wc: 64-col half
  const int lrow = lane & 15, lgrp = lane >> 4;

  const float* Abase = A + (size_t)(mt * 256) * 512;
  const float* Wbase = W + (size_t)(nt * 128) * 512;

  const f32x4 fz = {0.f, 0.f, 0.f, 0.f};
  f32x4 acc[8][4];
  #pragma unroll
  for (int i = 0; i < 8; ++i)
    #pragma unroll
    for (int j = 0; j < 4; ++j) acc[i][j] = fz;

  for (int k0 = 0; k0 < 512; k0 += 64) {
    __syncthreads();
    stage_f32_tile256(Abase + k0, 512, lAb, tid);
    stage_f32_tile(Wbase + k0, 512, lBb, tid);
    __syncthreads();
    #pragma unroll
    for (int kk = 0; kk < 2; ++kk) {
      bf16x8 af[8], bfr[4];
      #pragma unroll
      for (int mf = 0; mf < 8; ++mf) {
        int row  = wr * 128 + mf * 16 + lrow;
        int byte = (row << 7) + ((((kk << 2) | lgrp) ^ (row & 7)) << 4);
        af[mf] = *reinterpret_cast<const bf16x8*>(lAb + byte);
      }
      #pragma unroll
      for (int nf = 0; nf < 4; ++nf) {
        int row  = wc * 64 + nf * 16 + lrow;
        int byte = (row << 7) + ((((kk << 2) | lgrp) ^ (row & 7)) << 4);
        bfr[nf] = *reinterpret_cast<const bf16x8*>(lBb + byte);
      }
      #pragma unroll
      for (int mf = 0; mf < 8; ++mf)
        #pragma unroll
        for (int nf = 0; nf < 4; ++nf)
          acc[mf][nf] = __builtin_amdgcn_mfma_f32_16x16x32_bf16(
              af[mf], bfr[nf], acc[mf][nf], 0, 0, 0);
    }
  }

  float bcol[4];
  #pragma unroll
  for (int nf = 0; nf < 4; ++nf)
    bcol[nf] = bias[nt * 128 + wc * 64 + nf * 16 + lrow];

  #pragma unroll
  for (int mf = 0; mf < 8; ++mf) {
    #pragma unroll
    for (int nf = 0; nf < 4; ++nf) {
      #pragma unroll
      for (int r = 0; r < 4; ++r) {
        int grow = mt * 256 + wr * 128 + mf * 16 + lgrp * 4 + r;  // 0..8191
        int col  = nt * 128 + wc * 64 + nf * 16 + lrow;           // 0..511
        float vv = acc[mf][nf][r] + bcol[nf];
        bf16 hb  = (bf16)vv;
        int n = grow >> 10, tt = grow & 1023;
        if (g < 2) {
          int j = (g << 9) + col;
          Qws[(size_t)((((n << 3) + (j >> 7)) << 10) | tt) * 128 + (j & 127)] = hb;
        } else if (g < 4) {
          int j  = ((g - 2) << 9) + col;
          int hh = j >> 7, d = j & 127;
          int dd = (((d >> 3) ^ ((tt >> 1) & 7)) << 3) | (d & 7);
          Kws[(size_t)((((n << 3) + hh) << 10) | tt) * 128 + dd] = hb;
        } else {
          int h = col >> 6, d = col & 63;
          int kt2 = tt >> 5, si = tt & 31;
          int ss = (((si >> 3) ^ ((d >> 1) & 3)) << 3) | (si & 7);
          Vtws[((size_t)((((n << 3) + h) << 5) + kt2) * 64 + d) * 32 + ss] = hb;
        }
      }
    }
  }
}

// ---------------------------------------------------------------------------
// Kernel 2: flash attention (r15 version, verbatim — best known config).
// ---------------------------------------------------------------------------
__global__ __launch_bounds__(256) void attn_fwd(
    const bf16* __restrict__ Qws, const bf16* __restrict__ Kws,
    const bf16* __restrict__ Vtws, const float* __restrict__ mask,
    bf16* __restrict__ Ows) {
  __shared__ __align__(16) char Kl[3][8192];    // [buf][32 keys][16 ch * 16B]
  __shared__ __align__(16) char Vl[3][4096];    // [buf][64 d][32 s * 2B]
  __shared__ __align__(16) char Ml[2][16384];   // ring-2 [128 q][32 k * 4B]
  __shared__ __align__(16) char Pl[4][2048];    // per-wave P [32 q][32 s]

  const int bxr = blockIdx.x;                    // XCD = bxr % 8
  const int bx  = (bxr & 7) * 64 + (bxr >> 3);   // bijective chunked swizzle
  const int nh = bx >> 3;
  const int qt = bx & 7;
  const int tid = threadIdx.x;
  const int lane = tid & 63, wid = tid >> 6;     // wid 0..3
  const int lrow = lane & 15, lgrp = lane >> 4;
  const int q0 = qt * 128 + wid * 32;

  // Q fragments for this wave's 32 queries (2 Q-tiles)
  bf16x8 qf[2][4];
  #pragma unroll
  for (int qi = 0; qi < 2; ++qi) {
    const bf16* Qb = Qws + ((size_t)(nh * 1024 + q0 + qi * 16 + lrow)) * 128 + lgrp * 8;
    #pragma unroll
    for (int kk = 0; kk < 4; ++kk)
      qf[qi][kk] = *reinterpret_cast<const bf16x8*>(Qb + kk * 32);
  }

  // mask producer sources (waves 0,1 stage rows wid*64 .. wid*64+63)
  const float* Mg = mask + ((size_t)(nh * 1024) + qt * 128 + (wid & 1) * 64 +
                            (lane >> 3)) * 1024 + (lane & 7) * 4;
  // K source: fully linear (workspace pre-swizzled)
  const bf16* Kg = Kws + (size_t)nh * 131072 + lane * 8;
  // V source: fully linear (per-tile layout, pre-swizzled)
  const bf16* Vg = Vtws + (size_t)nh * 65536 + lane * 8;

  char* Pb = &Pl[wid][0];

  const f32x4 fz = {0.f, 0.f, 0.f, 0.f};
  f32x4 oacc[2][4];
  float m2[2][4], lsum[2][4];
  #pragma unroll
  for (int qi = 0; qi < 2; ++qi) {
    #pragma unroll
    for (int dt = 0; dt < 4; ++dt) oacc[qi][dt] = fz;
    #pragma unroll
    for (int r = 0; r < 4; ++r) { m2[qi][r] = 0.f; lsum[qi][r] = 0.f; }
  }

  auto stageM = [&](char* dst, int kt) {       // waves 0,1: 8 x 1KB each
    if (wid < 2) {
      char* d0 = dst + wid * 8192;
      #pragma unroll
      for (int i = 0; i < 8; ++i)
        GLDS(Mg + (size_t)i * 8192 + kt * 32, d0 + i * 1024);
    }
  };
  auto stageKV = [&](char* Kd, char* Vd, int kt) {
    if (wid == 2) {                            // K: 8KB linear, 8 x 1KB
      #pragma unroll
      for (int j = 0; j < 8; ++j)
        GLDS(Kg + kt * 4096 + j * 512, Kd + j * 1024);
    } else if (wid == 3) {                     // V: 4KB linear, 4 x 1KB
      #pragma unroll
      for (int j = 0; j < 4; ++j)
        GLDS(Vg + kt * 2048 + j * 512, Vd + j * 1024);
    }
  };
  // per-role wait: producers drain own mask (issued a full step earlier);
  // K/V stagers keep the newest stage in flight (2-step-ahead pipeline)
  auto roleWait = [&]() {
    if (wid == 2) { WAITV(8); }
    else if (wid == 3) { WAITV(4); }
    else { WAITV(0); }
  };

  // softmax + P + PV for one 32-key tile; K frags shared across both Q-tiles
  auto compute = [&](const char* Kb, const char* Vb, const char* Mb) {
    bf16x8 kf0[4], kf1[4], vf[4];
    #pragma unroll
    for (int kk = 0; kk < 4; ++kk) {
      int cb = ((((kk << 2) | lgrp) ^ (lrow & 7)) << 4);
      kf0[kk] = *reinterpret_cast<const bf16x8*>(Kb + lrow * 512 + cb);
      kf1[kk] = *reinterpret_cast<const bf16x8*>(Kb + lrow * 512 + 256 + cb);
    }
    #pragma unroll
    for (int dt = 0; dt < 4; ++dt)
      vf[dt] = *reinterpret_cast<const bf16x8*>(
          Vb + (dt * 16 + lrow) * 64 + ((lgrp ^ ((lrow >> 1) & 3)) << 4));
    f32x2 mk[2][4];
    #pragma unroll
    for (int qi = 0; qi < 2; ++qi)
      #pragma unroll
      for (int r = 0; r < 4; ++r) {
        int qrow = wid * 32 + qi * 16 + lgrp * 4 + r;   // 0..127
        mk[qi][r] = *reinterpret_cast<const f32x2*>(Mb + qrow * 128 + lrow * 8);
      }

    f32x4 sc0[2], sc1[2];
    __builtin_amdgcn_s_setprio(1);
    #pragma unroll
    for (int qi = 0; qi < 2; ++qi) {
      sc0[qi] = fz; sc1[qi] = fz;
      #pragma unroll
      for (int kk = 0; kk < 4; ++kk) {
        sc0[qi] = __builtin_amdgcn_mfma_f32_16x16x32_bf16(qf[qi][kk], kf0[kk], sc0[qi], 0, 0, 0);
        sc1[qi] = __builtin_amdgcn_mfma_f32_16x16x32_bf16(qf[qi][kk], kf1[kk], sc1[qi], 0, 0, 0);
      }
    }
    __builtin_amdgcn_s_setprio(0);

    float a0r[2][4], a1r[2][4];
    bool ok = true;
    #pragma unroll
    for (int qi = 0; qi < 2; ++qi)
      #pragma unroll
      for (int r = 0; r < 4; ++r) {
        a0r[qi][r] = fmaf(sc0[qi][r], QSCALE_LOG2E, mk[qi][r].x * LOG2E);
        a1r[qi][r] = fmaf(sc1[qi][r], QSCALE_LOG2E, mk[qi][r].y * LOG2E);
        ok &= (fmaxf(a0r[qi][r], a1r[qi][r]) <= m2[qi][r] + DEFER_THR);
      }
    if (__builtin_expect(!__all(ok), 0)) {
      #pragma unroll
      for (int qi = 0; qi < 2; ++qi)
        #pragma unroll
        for (int r = 0; r < 4; ++r) {
          float tv = fmaxf(a0r[qi][r], a1r[qi][r]);
          tv = fmaxf(tv, __shfl_xor(tv, 1));
          tv = fmaxf(tv, __shfl_xor(tv, 2));
          tv = fmaxf(tv, __shfl_xor(tv, 4));
          tv = fmaxf(tv, __shfl_xor(tv, 8));
          float mn = fmaxf(m2[qi][r], tv);
          float corr = exp2f(m2[qi][r] - mn);
          m2[qi][r] = mn;
          lsum[qi][r] *= corr;
          #pragma unroll
          for (int dt = 0; dt < 4; ++dt) oacc[qi][dt][r] *= corr;
        }
    }
    // P packed writes (per Q-tile sub-buffer, chunk-XOR'd)
    #pragma unroll
    for (int qi = 0; qi < 2; ++qi)
      #pragma unroll
      for (int r = 0; r < 4; ++r) {
        float e0 = exp2f(a0r[qi][r] - m2[qi][r]);
        float e1 = exp2f(a1r[qi][r] - m2[qi][r]);
        lsum[qi][r] += e0 + e1;
        union { bf16 h[2]; unsigned u; } pk;
        pk.h[0] = (bf16)e0; pk.h[1] = (bf16)e1;
        int row = lgrp * 4 + r;
        int byte = (qi << 10) + row * 64 +
                   ((((lrow >> 2) ^ (row & 3)) << 4) | ((lrow & 3) << 2));
        *reinterpret_cast<unsigned*>(Pb + byte) = pk.u;
      }
    __builtin_amdgcn_wave_barrier();
    __builtin_amdgcn_sched_barrier(0);
    bf16x8 pf[2];
    #pragma unroll
    for (int qi = 0; qi < 2; ++qi)
      pf[qi] = *reinterpret_cast<const bf16x8*>(
          Pb + (qi << 10) + lrow * 64 + ((lgrp ^ (lrow & 3)) << 4));

    __builtin_amdgcn_s_setprio(1);
    #pragma unroll
    for (int qi = 0; qi < 2; ++qi)
      #pragma unroll
      for (int dt = 0; dt < 4; ++dt)
        oacc[qi][dt] = __builtin_amdgcn_mfma_f32_16x16x32_bf16(
            pf[qi], vf[dt], oacc[qi][dt], 0, 0, 0);
    __builtin_amdgcn_s_setprio(0);
  };

  // ---- buffer pointers ----
  char *ka = &Kl[0][0], *kb2 = &Kl[1][0], *kc2 = &Kl[2][0];
  char *va = &Vl[0][0], *vb2 = &Vl[1][0], *vc2 = &Vl[2][0];
  char *m0 = &Ml[0][0], *m1 = &Ml[1][0];
  auto rotKV = [&]() {
    char* tp = ka; ka = kb2; kb2 = kc2; kc2 = tp;
    tp = va; va = vb2; vb2 = vc2; vc2 = tp;
  };
  auto rotM = [&]() { char* tp = m0; m0 = m1; m1 = tp; };

  // ---- prologue: KV(0) and KV(1); mask tile 0 ----
  stageKV(ka, va, 0);
  stageKV(kb2, vb2, 1);
  stageM(m0, 0);
  if (wid == 2) { WAITV(8); }        // KV(0) done, KV(1) in flight
  else if (wid == 3) { WAITV(4); }
  else { WAITV(0); }                 // M(0) done
  BARRIER();

  // ---- main loop t = 0..29: stage KV(t+2) and M(t+1) ----
  for (int t = 0; t < 30; ++t) {
    stageKV(kc2, vc2, t + 2);
    stageM(m1, t + 1);
    compute(ka, va, m0);
    roleWait();
    BARRIER();
    rotKV(); rotM();
  }
  // ---- t = 30: stage M(31) only; drain everything ----
  stageM(m1, 31);
  compute(ka, va, m0);
  WAITV(0);
  BARRIER();
  rotKV(); rotM();

  // ---- t = 31 ----
  compute(ka, va, m0);

  // final denominator reduce (deferred from the loop)
  #pragma unroll
  for (int qi = 0; qi < 2; ++qi)
    #pragma unroll
    for (int r = 0; r < 4; ++r) {
      float ss = lsum[qi][r];
      ss += __shfl_xor(ss, 1);
      ss += __shfl_xor(ss, 2);
      ss += __shfl_xor(ss, 4);
      ss += __shfl_xor(ss, 8);
      lsum[qi][r] = 1.0f / ss;
    }

  const int n = nh >> 3, h = nh & 7;
  #pragma unroll
  for (int qi = 0; qi < 2; ++qi) {
    bf16* Ob = Ows + ((size_t)(n * 1024 + q0 + qi * 16 + lgrp * 4)) * 512 +
               h * 64 + lrow;
    #pragma unroll
    for (int dt = 0; dt < 4; ++dt)
      #pragma unroll
      for (int r = 0; r < 4; ++r)
        Ob[(size_t)r * 512 + dt * 16] = (bf16)(oacc[qi][dt][r] * lsum[qi][r]);
  }
}

// ---------------------------------------------------------------------------
// Kernel 3: output projection. grid = 64 * 4 = 256 blocks, XCD-chunked.
// ---------------------------------------------------------------------------
__global__ __launch_bounds__(256) void out_gemm(
    const bf16* __restrict__ Ows, const float* __restrict__ Wo,
    const float* __restrict__ bo, float* __restrict__ out) {
  __shared__ __align__(16) bf16 lA[128 * 64];
  __shared__ __align__(16) bf16 lB[128 * 64];
  char* lAb = (char*)lA;
  char* lBb = (char*)lB;

  const int bxr = blockIdx.x;                   // XCD = bxr % 8
  const int bx  = (bxr & 7) * 32 + (bxr >> 3);  // bijective chunked swizzle
  const int mt = bx >> 2;
  const int nt = bx & 3;
  const int tid = threadIdx.x;
  const int lane = tid & 63, wid = tid >> 6;
  const int wr = wid >> 1, wc = wid & 1;
  const int lrow = lane & 15, lgrp = lane >> 4;

  const bf16*  Abase = Ows + (size_t)(mt * 128) * 512;
  const float* Wbase = Wo  + (size_t)(nt * 128) * 512;

  const f32x4 fz = {0.f, 0.f, 0.f, 0.f};
  f32x4 acc[4][4];
  #pragma unroll
  for (int i = 0; i < 4; ++i)
    #pragma unroll
    for (int j = 0; j < 4; ++j) acc[i][j] = fz;

  for (int k0 = 0; k0 < 512; k0 += 64) {
    __syncthreads();
    stage_bf16_tile(Abase + k0, 512, lAb, tid);
    stage_f32_tile(Wbase + k0, 512, lBb, tid);
    __syncthreads();
    #pragma unroll
    for (int kk = 0; kk < 2; ++kk) {
      bf16x8 af[4], bfr[4];
      #pragma unroll
      for (int mf = 0; mf < 4; ++mf) {
        int row  = wr * 64 + mf * 16 + lrow;
        int byte = (row << 7) + ((((kk << 2) | lgrp) ^ (row & 7)) << 4);
        af[mf] = *reinterpret_cast<const bf16x8*>(lAb + byte);
      }
      #pragma unroll
      for (int nf = 0; nf < 4; ++nf) {
        int row  = wc * 64 + nf * 16 + lrow;
        int byte = (row << 7) + ((((kk << 2) | lgrp) ^ (row & 7)) << 4);
        bfr[nf] = *reinterpret_cast<const bf16x8*>(lBb + byte);
      }
      #pragma unroll
      for (int mf = 0; mf < 4; ++mf)
        #pragma unroll
        for (int nf = 0; nf < 4; ++nf)
          acc[mf][nf] = __builtin_amdgcn_mfma_f32_16x16x32_bf16(
              af[mf], bfr[nf], acc[mf][nf], 0, 0, 0);
    }
  }

  float bcol[4];
  #pragma unroll
  for (int nf = 0; nf < 4; ++nf)
    bcol[nf] = bo[nt * 128 + wc * 64 + nf * 16 + lrow];

  #pragma unroll
  for (int mf = 0; mf < 4; ++mf) {
    #pragma unroll
    for (int nf = 0; nf < 4; ++nf) {
      #pragma unroll
      for (int r = 0; r < 4; ++r) {
        int grow = mt * 128 + wr * 64 + mf * 16 + lgrp * 4 + r;
        int col  = nt * 128 + wc * 64 + nf * 16 + lrow;
        out[(size_t)grow * 512 + col] = acc[mf][nf][r] + bcol[nf];
      }
    }
  }
}

// ---------------------------------------------------------------------------
extern "C" void kernel_launch(void* const* d_in, const int* in_sizes, int n_in,
                              void* d_out, int out_size, void* d_ws, size_t ws_size,
                              hipStream_t stream) {
  const float* qc   = (const float*)d_in[0];
  const float* qp   = (const float*)d_in[1];
  const float* kc   = (const float*)d_in[2];
  const float* kp   = (const float*)d_in[3];
  const float* vin  = (const float*)d_in[4];
  const float* mask = (const float*)d_in[5];
  const float* Wqc  = (const float*)d_in[6];
  const float* bqc  = (const float*)d_in[7];
  const float* Wqp  = (const float*)d_in[8];
  const float* bqp  = (const float*)d_in[9];
  const float* Wkc  = (const float*)d_in[10];
  const float* bkc  = (const float*)d_in[11];
  const float* Wkp  = (const float*)d_in[12];
  const float* bkp  = (const float*)d_in[13];
  const float* Wv   = (const float*)d_in[14];
  const float* bv   = (const float*)d_in[15];
  const float* Wo   = (const float*)d_in[16];
  const float* bo   = (const float*)d_in[17];

  bf16* Qws  = (bf16*)d_ws;                     // (8,8,1024,128)  16 MB
  bf16* Kws  = Qws  + (size_t)8 * 1024 * 1024;  // (8,8,1024,128)  16 MB, pre-swz
  bf16* Vtws = Kws  + (size_t)8 * 1024 * 1024;  // (8,8,32,64,32)   8 MB, pre-swz
  bf16* Ows  = Vtws + (size_t)4 * 1024 * 1024;  // (8192,512)       8 MB

  proj_gemm<<<dim3(640), dim3(256), 0, stream>>>(
      qc, qp, kc, kp, vin, Wqc, bqc, Wqp, bqp, Wkc, bkc, Wkp, bkp, Wv, bv,
      Qws, Kws, Vtws);
  attn_fwd<<<dim3(512), dim3(256), 0, stream>>>(Qws, Kws, Vtws, mask, Ows);
  out_gemm<<<dim3(256), dim3(256), 0, stream>>>(Ows, Wo, bo, (float*)d_out);
}

// Round 17
// 178.824 us; speedup vs baseline: 1.1726x; 1.1726x over previous
//
#include <hip/hip_runtime.h>
#include <hip/hip_bf16.h>

typedef __bf16 bf16;
typedef __bf16 bf16x8 __attribute__((ext_vector_type(8)));
typedef float  f32x4  __attribute__((ext_vector_type(4)));
typedef float  f32x2  __attribute__((ext_vector_type(2)));

#define LOG2E        1.4426950408889634f
#define QSCALE_LOG2E 0.18033688011112043f   /* log2(e)/8 */
#define DEFER_THR    20.0f                  /* rescale only if logit2 > m+20 */

// async global->LDS, 16B per lane; LDS dest = uniform base + lane*16
#define GLDS(g, l)                                                        \
  __builtin_amdgcn_global_load_lds(                                       \
      (const __attribute__((address_space(1))) void*)(g),                 \
      (__attribute__((address_space(3))) void*)(l), 16, 0, 0)

#define WAITV(n) asm volatile("s_waitcnt vmcnt(" #n ")" ::: "memory")
#define BARRIER() do {                                                    \
  __builtin_amdgcn_s_barrier();                                           \
  __builtin_amdgcn_sched_barrier(0);                                      \
} while (0)

// ---------------------------------------------------------------------------
// LDS staging helpers for the GEMMs (unchanged, known good)
// ---------------------------------------------------------------------------
__device__ __forceinline__ void stage_f32_tile(const float* __restrict__ src, int ld,
                                               char* dst, int tid) {
  #pragma unroll
  for (int t = 0; t < 8; ++t) {
    int c8  = tid + t * 256;
    int row = c8 >> 4;
    int h8  = c8 & 15;
    const f32x4 v = *reinterpret_cast<const f32x4*>(src + row * ld + h8 * 4);
    union { bf16 h[4]; unsigned long long u; } pk;
    pk.h[0] = (bf16)v[0]; pk.h[1] = (bf16)v[1];
    pk.h[2] = (bf16)v[2]; pk.h[3] = (bf16)v[3];
    int byte = (row << 7) + ((((h8 >> 1) ^ (row & 7)) << 4) | ((h8 & 1) << 3));
    *reinterpret_cast<unsigned long long*>(dst + byte) = pk.u;
  }
}

__device__ __forceinline__ void stage_bf16_tile(const bf16* __restrict__ src, int ld,
                                                char* dst, int tid) {
  #pragma unroll
  for (int t = 0; t < 4; ++t) {
    int c   = tid + t * 256;
    int row = c >> 3;
    int ck  = c & 7;
    const bf16x8 v = *reinterpret_cast<const bf16x8*>(src + row * ld + ck * 8);
    int byte = (row << 7) + (((ck ^ (row & 7)) << 4));
    *reinterpret_cast<bf16x8*>(dst + byte) = v;
  }
}

// ---------------------------------------------------------------------------
// Kernel 1: all 5 projection GEMMs (r9 version — local optimum; both
// redesigns r11/r16 regressed 25-40us). grid = 5*64*4 = 1280 blocks.
// K and V workspaces written PRE-SWIZZLED so attn DMA sources are linear:
//   Kws: chunk d>>3 stored at (d>>3) ^ ((key>>1)&7)
//   Vt2: (nh, ktile, 64 d, 32 s) with slot s>>3 stored at (s>>3)^((d>>1)&3)
// ---------------------------------------------------------------------------
__global__ __launch_bounds__(256) void proj_gemm(
    const float* __restrict__ qc, const float* __restrict__ qp,
    const float* __restrict__ kc, const float* __restrict__ kp,
    const float* __restrict__ vin,
    const float* __restrict__ Wqc, const float* __restrict__ bqc,
    const float* __restrict__ Wqp, const float* __restrict__ bqp,
    const float* __restrict__ Wkc, const float* __restrict__ bkc,
    const float* __restrict__ Wkp, const float* __restrict__ bkp,
    const float* __restrict__ Wv,  const float* __restrict__ bv,
    bf16* __restrict__ Qws, bf16* __restrict__ Kws, bf16* __restrict__ Vtws) {
  __shared__ __align__(16) bf16 lA[128 * 64];
  __shared__ __align__(16) bf16 lB[128 * 64];
  char* lAb = (char*)lA;
  char* lBb = (char*)lB;

  const int bxr = blockIdx.x;                    // dispatch idx; XCD = bxr % 8
  const int bx  = (bxr & 7) * 160 + (bxr >> 3);  // bijective chunked swizzle
  const int g  = bx >> 8;
  const int mt = (bx & 255) >> 2;
  const int nt = bx & 3;

  const float *A, *W, *bias;
  if      (g == 0) { A = qc;  W = Wqc; bias = bqc; }
  else if (g == 1) { A = qp;  W = Wqp; bias = bqp; }
  else if (g == 2) { A = kc;  W = Wkc; bias = bkc; }
  else if (g == 3) { A = kp;  W = Wkp; bias = bkp; }
  else             { A = vin; W = Wv;  bias = bv;  }

  const int tid  = threadIdx.x;
  const int lane = tid & 63, wid = tid >> 6;
  const int wr = wid >> 1, wc = wid & 1;
  const int lrow = lane & 15, lgrp = lane >> 4;

  const float* Abase = A + (size_t)(mt * 128) * 512;
  const float* Wbase = W + (size_t)(nt * 128) * 512;

  const f32x4 fz = {0.f, 0.f, 0.f, 0.f};
  f32x4 acc[4][4];
  #pragma unroll
  for (int i = 0; i < 4; ++i)
    #pragma unroll
    for (int j = 0; j < 4; ++j) acc[i][j] = fz;

  for (int k0 = 0; k0 < 512; k0 += 64) {
    __syncthreads();
    stage_f32_tile(Abase + k0, 512, lAb, tid);
    stage_f32_tile(Wbase + k0, 512, lBb, tid);
    __syncthreads();
    #pragma unroll
    for (int kk = 0; kk < 2; ++kk) {
      bf16x8 af[4], bfr[4];
      #pragma unroll
      for (int mf = 0; mf < 4; ++mf) {
        int row  = wr * 64 + mf * 16 + lrow;
        int byte = (row << 7) + ((((kk << 2) | lgrp) ^ (row & 7)) << 4);
        af[mf] = *reinterpret_cast<const bf16x8*>(lAb + byte);
      }
      #pragma unroll
      for (int nf = 0; nf < 4; ++nf) {
        int row  = wc * 64 + nf * 16 + lrow;
        int byte = (row << 7) + ((((kk << 2) | lgrp) ^ (row & 7)) << 4);
        bfr[nf] = *reinterpret_cast<const bf16x8*>(lBb + byte);
      }
      #pragma unroll
      for (int mf = 0; mf < 4; ++mf)
        #pragma unroll
        for (int nf = 0; nf < 4; ++nf)
          acc[mf][nf] = __builtin_amdgcn_mfma_f32_16x16x32_bf16(
              af[mf], bfr[nf], acc[mf][nf], 0, 0, 0);
    }
  }

  float bcol[4];
  #pragma unroll
  for (int nf = 0; nf < 4; ++nf)
    bcol[nf] = bias[nt * 128 + wc * 64 + nf * 16 + lrow];

  #pragma unroll
  for (int mf = 0; mf < 4; ++mf) {
    #pragma unroll
    for (int nf = 0; nf < 4; ++nf) {
      #pragma unroll
      for (int r = 0; r < 4; ++r) {
        int grow = mt * 128 + wr * 64 + mf * 16 + lgrp * 4 + r;
        int col  = nt * 128 + wc * 64 + nf * 16 + lrow;
        float vv = acc[mf][nf][r] + bcol[nf];
        bf16 hb  = (bf16)vv;
        int n = grow >> 10, tt = grow & 1023;
        if (g < 2) {
          int j = (g << 9) + col;
          Qws[(size_t)((((n << 3) + (j >> 7)) << 10) | tt) * 128 + (j & 127)] = hb;
        } else if (g < 4) {
          int j  = ((g - 2) << 9) + col;
          int hh = j >> 7, d = j & 127;
          int dd = (((d >> 3) ^ ((tt >> 1) & 7)) << 3) | (d & 7);
          Kws[(size_t)((((n << 3) + hh) << 10) | tt) * 128 + dd] = hb;
        } else {
          int h = col >> 6, d = col & 63;
          int kt2 = tt >> 5, si = tt & 31;
          int ss = (((si >> 3) ^ ((d >> 1) & 3)) << 3) | (si & 7);
          Vtws[((size_t)((((n << 3) + h) << 5) + kt2) * 64 + d) * 32 + ss] = hb;
        }
      }
    }
  }
}

// ---------------------------------------------------------------------------
// Kernel 2: flash attention (r15 version — best known config).
// 32 q/wave, 4 waves, 128q block; K/V triple-buffered (2 ahead, K vmcnt(8),
// V vmcnt(4)); mask ring-2; linear DMA sources. LDS 76 KB -> 2 blocks/CU.
// ---------------------------------------------------------------------------
__global__ __launch_bounds__(256) void attn_fwd(
    const bf16* __restrict__ Qws, const bf16* __restrict__ Kws,
    const bf16* __restrict__ Vtws, const float* __restrict__ mask,
    bf16* __restrict__ Ows) {
  __shared__ __align__(16) char Kl[3][8192];    // [buf][32 keys][16 ch * 16B]
  __shared__ __align__(16) char Vl[3][4096];    // [buf][64 d][32 s * 2B]
  __shared__ __align__(16) char Ml[2][16384];   // ring-2 [128 q][32 k * 4B]
  __shared__ __align__(16) char Pl[4][2048];    // per-wave P [32 q][32 s]

  const int bxr = blockIdx.x;                    // XCD = bxr % 8
  const int bx  = (bxr & 7) * 64 + (bxr >> 3);   // bijective chunked swizzle
  const int nh = bx >> 3;
  const int qt = bx & 7;
  const int tid = threadIdx.x;
  const int lane = tid & 63, wid = tid >> 6;     // wid 0..3
  const int lrow = lane & 15, lgrp = lane >> 4;
  const int q0 = qt * 128 + wid * 32;

  // Q fragments for this wave's 32 queries (2 Q-tiles)
  bf16x8 qf[2][4];
  #pragma unroll
  for (int qi = 0; qi < 2; ++qi) {
    const bf16* Qb = Qws + ((size_t)(nh * 1024 + q0 + qi * 16 + lrow)) * 128 + lgrp * 8;
    #pragma unroll
    for (int kk = 0; kk < 4; ++kk)
      qf[qi][kk] = *reinterpret_cast<const bf16x8*>(Qb + kk * 32);
  }

  // mask producer sources (waves 0,1 stage rows wid*64 .. wid*64+63)
  const float* Mg = mask + ((size_t)(nh * 1024) + qt * 128 + (wid & 1) * 64 +
                            (lane >> 3)) * 1024 + (lane & 7) * 4;
  // K source: fully linear (workspace pre-swizzled)
  const bf16* Kg = Kws + (size_t)nh * 131072 + lane * 8;
  // V source: fully linear (per-tile layout, pre-swizzled)
  const bf16* Vg = Vtws + (size_t)nh * 65536 + lane * 8;

  char* Pb = &Pl[wid][0];

  const f32x4 fz = {0.f, 0.f, 0.f, 0.f};
  f32x4 oacc[2][4];
  float m2[2][4], lsum[2][4];
  #pragma unroll
  for (int qi = 0; qi < 2; ++qi) {
    #pragma unroll
    for (int dt = 0; dt < 4; ++dt) oacc[qi][dt] = fz;
    #pragma unroll
    for (int r = 0; r < 4; ++r) { m2[qi][r] = 0.f; lsum[qi][r] = 0.f; }
  }

  auto stageM = [&](char* dst, int kt) {       // waves 0,1: 8 x 1KB each
    if (wid < 2) {
      char* d0 = dst + wid * 8192;
      #pragma unroll
      for (int i = 0; i < 8; ++i)
        GLDS(Mg + (size_t)i * 8192 + kt * 32, d0 + i * 1024);
    }
  };
  auto stageKV = [&](char* Kd, char* Vd, int kt) {
    if (wid == 2) {                            // K: 8KB linear, 8 x 1KB
      #pragma unroll
      for (int j = 0; j < 8; ++j)
        GLDS(Kg + kt * 4096 + j * 512, Kd + j * 1024);
    } else if (wid == 3) {                     // V: 4KB linear, 4 x 1KB
      #pragma unroll
      for (int j = 0; j < 4; ++j)
        GLDS(Vg + kt * 2048 + j * 512, Vd + j * 1024);
    }
  };
  // per-role wait: producers drain own mask (issued a full step earlier);
  // K/V stagers keep the newest stage in flight (2-step-ahead pipeline)
  auto roleWait = [&]() {
    if (wid == 2) { WAITV(8); }
    else if (wid == 3) { WAITV(4); }
    else { WAITV(0); }
  };

  // softmax + P + PV for one 32-key tile; K frags shared across both Q-tiles
  auto compute = [&](const char* Kb, const char* Vb, const char* Mb) {
    bf16x8 kf0[4], kf1[4], vf[4];
    #pragma unroll
    for (int kk = 0; kk < 4; ++kk) {
      int cb = ((((kk << 2) | lgrp) ^ (lrow & 7)) << 4);
      kf0[kk] = *reinterpret_cast<const bf16x8*>(Kb + lrow * 512 + cb);
      kf1[kk] = *reinterpret_cast<const bf16x8*>(Kb + lrow * 512 + 256 + cb);
    }
    #pragma unroll
    for (int dt = 0; dt < 4; ++dt)
      vf[dt] = *reinterpret_cast<const bf16x8*>(
          Vb + (dt * 16 + lrow) * 64 + ((lgrp ^ ((lrow >> 1) & 3)) << 4));
    f32x2 mk[2][4];
    #pragma unroll
    for (int qi = 0; qi < 2; ++qi)
      #pragma unroll
      for (int r = 0; r < 4; ++r) {
        int qrow = wid * 32 + qi * 16 + lgrp * 4 + r;   // 0..127
        mk[qi][r] = *reinterpret_cast<const f32x2*>(Mb + qrow * 128 + lrow * 8);
      }

    f32x4 sc0[2], sc1[2];
    __builtin_amdgcn_s_setprio(1);
    #pragma unroll
    for (int qi = 0; qi < 2; ++qi) {
      sc0[qi] = fz; sc1[qi] = fz;
      #pragma unroll
      for (int kk = 0; kk < 4; ++kk) {
        sc0[qi] = __builtin_amdgcn_mfma_f32_16x16x32_bf16(qf[qi][kk], kf0[kk], sc0[qi], 0, 0, 0);
        sc1[qi] = __builtin_amdgcn_mfma_f32_16x16x32_bf16(qf[qi][kk], kf1[kk], sc1[qi], 0, 0, 0);
      }
    }
    __builtin_amdgcn_s_setprio(0);

    float a0r[2][4], a1r[2][4];
    bool ok = true;
    #pragma unroll
    for (int qi = 0; qi < 2; ++qi)
      #pragma unroll
      for (int r = 0; r < 4; ++r) {
        a0r[qi][r] = fmaf(sc0[qi][r], QSCALE_LOG2E, mk[qi][r].x * LOG2E);
        a1r[qi][r] = fmaf(sc1[qi][r], QSCALE_LOG2E, mk[qi][r].y * LOG2E);
        ok &= (fmaxf(a0r[qi][r], a1r[qi][r]) <= m2[qi][r] + DEFER_THR);
      }
    if (__builtin_expect(!__all(ok), 0)) {
      #pragma unroll
      for (int qi = 0; qi < 2; ++qi)
        #pragma unroll
        for (int r = 0; r < 4; ++r) {
          float tv = fmaxf(a0r[qi][r], a1r[qi][r]);
          tv = fmaxf(tv, __shfl_xor(tv, 1));
          tv = fmaxf(tv, __shfl_xor(tv, 2));
          tv = fmaxf(tv, __shfl_xor(tv, 4));
          tv = fmaxf(tv, __shfl_xor(tv, 8));
          float mn = fmaxf(m2[qi][r], tv);
          float corr = exp2f(m2[qi][r] - mn);
          m2[qi][r] = mn;
          lsum[qi][r] *= corr;
          #pragma unroll
          for (int dt = 0; dt < 4; ++dt) oacc[qi][dt][r] *= corr;
        }
    }
    // P packed writes (per Q-tile sub-buffer, chunk-XOR'd)
    #pragma unroll
    for (int qi = 0; qi < 2; ++qi)
      #pragma unroll
      for (int r = 0; r < 4; ++r) {
        float e0 = exp2f(a0r[qi][r] - m2[qi][r]);
        float e1 = exp2f(a1r[qi][r] - m2[qi][r]);
        lsum[qi][r] += e0 + e1;
        union { bf16 h[2]; unsigned u; } pk;
        pk.h[0] = (bf16)e0; pk.h[1] = (bf16)e1;
        int row = lgrp * 4 + r;
        int byte = (qi << 10) + row * 64 +
                   ((((lrow >> 2) ^ (row & 3)) << 4) | ((lrow & 3) << 2));
        *reinterpret_cast<unsigned*>(Pb + byte) = pk.u;
      }
    __builtin_amdgcn_wave_barrier();
    __builtin_amdgcn_sched_barrier(0);
    bf16x8 pf[2];
    #pragma unroll
    for (int qi = 0; qi < 2; ++qi)
      pf[qi] = *reinterpret_cast<const bf16x8*>(
          Pb + (qi << 10) + lrow * 64 + ((lgrp ^ (lrow & 3)) << 4));

    __builtin_amdgcn_s_setprio(1);
    #pragma unroll
    for (int qi = 0; qi < 2; ++qi)
      #pragma unroll
      for (int dt = 0; dt < 4; ++dt)
        oacc[qi][dt] = __builtin_amdgcn_mfma_f32_16x16x32_bf16(
            pf[qi], vf[dt], oacc[qi][dt], 0, 0, 0);
    __builtin_amdgcn_s_setprio(0);
  };

  // ---- buffer pointers ----
  char *ka = &Kl[0][0], *kb2 = &Kl[1][0], *kc2 = &Kl[2][0];
  char *va = &Vl[0][0], *vb2 = &Vl[1][0], *vc2 = &Vl[2][0];
  char *m0 = &Ml[0][0], *m1 = &Ml[1][0];
  auto rotKV = [&]() {
    char* tp = ka; ka = kb2; kb2 = kc2; kc2 = tp;
    tp = va; va = vb2; vb2 = vc2; vc2 = tp;
  };
  auto rotM = [&]() { char* tp = m0; m0 = m1; m1 = tp; };

  // ---- prologue: KV(0) and KV(1); mask tile 0 ----
  stageKV(ka, va, 0);
  stageKV(kb2, vb2, 1);
  stageM(m0, 0);
  if (wid == 2) { WAITV(8); }        // KV(0) done, KV(1) in flight
  else if (wid == 3) { WAITV(4); }
  else { WAITV(0); }                 // M(0) done
  BARRIER();

  // ---- main loop t = 0..29: stage KV(t+2) and M(t+1) ----
  for (int t = 0; t < 30; ++t) {
    stageKV(kc2, vc2, t + 2);
    stageM(m1, t + 1);
    compute(ka, va, m0);
    roleWait();
    BARRIER();
    rotKV(); rotM();
  }
  // ---- t = 30: stage M(31) only; drain everything ----
  stageM(m1, 31);
  compute(ka, va, m0);
  WAITV(0);
  BARRIER();
  rotKV(); rotM();

  // ---- t = 31 ----
  compute(ka, va, m0);

  // final denominator reduce (deferred from the loop)
  #pragma unroll
  for (int qi = 0; qi < 2; ++qi)
    #pragma unroll
    for (int r = 0; r < 4; ++r) {
      float ss = lsum[qi][r];
      ss += __shfl_xor(ss, 1);
      ss += __shfl_xor(ss, 2);
      ss += __shfl_xor(ss, 4);
      ss += __shfl_xor(ss, 8);
      lsum[qi][r] = 1.0f / ss;
    }

  const int n = nh >> 3, h = nh & 7;
  #pragma unroll
  for (int qi = 0; qi < 2; ++qi) {
    bf16* Ob = Ows + ((size_t)(n * 1024 + q0 + qi * 16 + lgrp * 4)) * 512 +
               h * 64 + lrow;
    #pragma unroll
    for (int dt = 0; dt < 4; ++dt)
      #pragma unroll
      for (int r = 0; r < 4; ++r)
        Ob[(size_t)r * 512 + dt * 16] = (bf16)(oacc[qi][dt][r] * lsum[qi][r]);
  }
}

// ---------------------------------------------------------------------------
// Kernel 3: output projection. grid = 64 * 4 = 256 blocks, XCD-chunked.
// ---------------------------------------------------------------------------
__global__ __launch_bounds__(256) void out_gemm(
    const bf16* __restrict__ Ows, const float* __restrict__ Wo,
    const float* __restrict__ bo, float* __restrict__ out) {
  __shared__ __align__(16) bf16 lA[128 * 64];
  __shared__ __align__(16) bf16 lB[128 * 64];
  char* lAb = (char*)lA;
  char* lBb = (char*)lB;

  const int bxr = blockIdx.x;                   // XCD = bxr % 8
  const int bx  = (bxr & 7) * 32 + (bxr >> 3);  // bijective chunked swizzle
  const int mt = bx >> 2;
  const int nt = bx & 3;
  const int tid = threadIdx.x;
  const int lane = tid & 63, wid = tid >> 6;
  const int wr = wid >> 1, wc = wid & 1;
  const int lrow = lane & 15, lgrp = lane >> 4;

  const bf16*  Abase = Ows + (size_t)(mt * 128) * 512;
  const float* Wbase = Wo  + (size_t)(nt * 128) * 512;

  const f32x4 fz = {0.f, 0.f, 0.f, 0.f};
  f32x4 acc[4][4];
  #pragma unroll
  for (int i = 0; i < 4; ++i)
    #pragma unroll
    for (int j = 0; j < 4; ++j) acc[i][j] = fz;

  for (int k0 = 0; k0 < 512; k0 += 64) {
    __syncthreads();
    stage_bf16_tile(Abase + k0, 512, lAb, tid);
    stage_f32_tile(Wbase + k0, 512, lBb, tid);
    __syncthreads();
    #pragma unroll
    for (int kk = 0; kk < 2; ++kk) {
      bf16x8 af[4], bfr[4];
      #pragma unroll
      for (int mf = 0; mf < 4; ++mf) {
        int row  = wr * 64 + mf * 16 + lrow;
        int byte = (row << 7) + ((((kk << 2) | lgrp) ^ (row & 7)) << 4);
        af[mf] = *reinterpret_cast<const bf16x8*>(lAb + byte);
      }
      #pragma unroll
      for (int nf = 0; nf < 4; ++nf) {
        int row  = wc * 64 + nf * 16 + lrow;
        int byte = (row << 7) + ((((kk << 2) | lgrp) ^ (row & 7)) << 4);
        bfr[nf] = *reinterpret_cast<const bf16x8*>(lBb + byte);
      }
      #pragma unroll
      for (int mf = 0; mf < 4; ++mf)
        #pragma unroll
        for (int nf = 0; nf < 4; ++nf)
          acc[mf][nf] = __builtin_amdgcn_mfma_f32_16x16x32_bf16(
              af[mf], bfr[nf], acc[mf][nf], 0, 0, 0);
    }
  }

  float bcol[4];
  #pragma unroll
  for (int nf = 0; nf < 4; ++nf)
    bcol[nf] = bo[nt * 128 + wc * 64 + nf * 16 + lrow];

  #pragma unroll
  for (int mf = 0; mf < 4; ++mf) {
    #pragma unroll
    for (int nf = 0; nf < 4; ++nf) {
      #pragma unroll
      for (int r = 0; r < 4; ++r) {
        int grow = mt * 128 + wr * 64 + mf * 16 + lgrp * 4 + r;
        int col  = nt * 128 + wc * 64 + nf * 16 + lrow;
        out[(size_t)grow * 512 + col] = acc[mf][nf][r] + bcol[nf];
      }
    }
  }
}

// ---------------------------------------------------------------------------
extern "C" void kernel_launch(void* const* d_in, const int* in_sizes, int n_in,
                              void* d_out, int out_size, void* d_ws, size_t ws_size,
                              hipStream_t stream) {
  const float* qc   = (const float*)d_in[0];
  const float* qp   = (const float*)d_in[1];
  const float* kc   = (const float*)d_in[2];
  const float* kp   = (const float*)d_in[3];
  const float* vin  = (const float*)d_in[4];
  const float* mask = (const float*)d_in[5];
  const float* Wqc  = (const float*)d_in[6];
  const float* bqc  = (const float*)d_in[7];
  const float* Wqp  = (const float*)d_in[8];
  const float* bqp  = (const float*)d_in[9];
  const float* Wkc  = (const float*)d_in[10];
  const float* bkc  = (const float*)d_in[11];
  const float* Wkp  = (const float*)d_in[12];
  const float* bkp  = (const float*)d_in[13];
  const float* Wv   = (const float*)d_in[14];
  const float* bv   = (const float*)d_in[15];
  const float* Wo   = (const float*)d_in[16];
  const float* bo   = (const float*)d_in[17];

  bf16* Qws  = (bf16*)d_ws;                     // (8,8,1024,128)  16 MB
  bf16* Kws  = Qws  + (size_t)8 * 1024 * 1024;  // (8,8,1024,128)  16 MB, pre-swz
  bf16* Vtws = Kws  + (size_t)8 * 1024 * 1024;  // (8,8,32,64,32)   8 MB, pre-swz
  bf16* Ows  = Vtws + (size_t)4 * 1024 * 1024;  // (8192,512)       8 MB

  proj_gemm<<<dim3(1280), dim3(256), 0, stream>>>(
      qc, qp, kc, kp, vin, Wqc, bqc, Wqp, bqp, Wkc, bkc, Wkp, bkp, Wv, bv,
      Qws, Kws, Vtws);
  attn_fwd<<<dim3(512), dim3(256), 0, stream>>>(Qws, Kws, Vtws, mask, Ows);
  out_gemm<<<dim3(256), dim3(256), 0, stream>>>(Ows, Wo, bo, (float*)d_out);
}